// Round 9
// baseline (22866.164 us; speedup 1.0000x reference)
//
#include <hip/hip_runtime.h>
#include <hip/hip_bf16.h>
#include <hip/hip_fp16.h>

#define SEQ   4096
#define IDIM  2048
#define HDIM  2048
#define G4    8192
#define NBLK  256
#define NREP  64     // message replicas: readers-per-line = NBLK/NREP = 4

// ---------------- numerics (v_exp2 / v_rcp based, ~1e-6 rel err) ----------------
__device__ __forceinline__ float fast_sig(float x) {
    float e = __builtin_amdgcn_exp2f(-1.4426950408889634f * x);   // exp(-x)
    return __builtin_amdgcn_rcpf(1.0f + e);
}
__device__ __forceinline__ float fast_tanh(float x) {
    float e = __builtin_amdgcn_exp2f(2.8853900817779268f * x);    // exp(2x)
    return 1.0f - 2.0f * __builtin_amdgcn_rcpf(e + 1.0f);
}
__device__ __forceinline__ unsigned short f2h(float f) {
    __half h = __float2half_rn(f);
    union { __half h; unsigned short s; } c; c.h = h; return c.s;
}
__device__ __forceinline__ float h2f(unsigned short u) {
    union { unsigned short s; __half h; } c; c.s = u; return __half2float(c.h);
}

// ---------------- phase 1: xg[s][g] = x[s,:] . Wih[g,:] + bih[g] + bhh[g] (bf16 store) ---
#define BM 128
#define BN 128
#define BK 16
#define LSTR (BM + 4)   // 132 words: rows stay 16B-aligned, write conflicts 2-way (free)

__global__ __launch_bounds__(256, 4)
void xg_gemm(const float* __restrict__ x, const float* __restrict__ Wih,
             const float* __restrict__ bih, const float* __restrict__ bhh,
             __hip_bfloat16* __restrict__ xg)
{
    __shared__ float As[BK][LSTR];   // [k][s]
    __shared__ float Bs[BK][LSTR];   // [k][g]
    const int t  = threadIdx.x;
    const int bG = blockIdx.x;            // 64 tiles over G4
    const int bS = blockIdx.y;            // 32 tiles over SEQ
    const int s0 = bS * BM, g0 = bG * BN;
    const int tx = t & 15, ty = t >> 4;   // 16x16 thread grid, 8x8 microtile
    const int lr = t >> 1, lk = (t & 1) * 8;

    float acc[8][8];
#pragma unroll
    for (int r = 0; r < 8; ++r)
#pragma unroll
        for (int c = 0; c < 8; ++c) acc[r][c] = 0.0f;

    const float* xp = x   + (size_t)(s0 + lr) * IDIM + lk;
    const float* wp = Wih + (size_t)(g0 + lr) * IDIM + lk;

    for (int k0 = 0; k0 < IDIM; k0 += BK) {
        float4 a0 = *(const float4*)(xp + k0);
        float4 a1 = *(const float4*)(xp + k0 + 4);
        float4 b0 = *(const float4*)(wp + k0);
        float4 b1 = *(const float4*)(wp + k0 + 4);
        __syncthreads();
        As[lk+0][lr] = a0.x; As[lk+1][lr] = a0.y; As[lk+2][lr] = a0.z; As[lk+3][lr] = a0.w;
        As[lk+4][lr] = a1.x; As[lk+5][lr] = a1.y; As[lk+6][lr] = a1.z; As[lk+7][lr] = a1.w;
        Bs[lk+0][lr] = b0.x; Bs[lk+1][lr] = b0.y; Bs[lk+2][lr] = b0.z; Bs[lk+3][lr] = b0.w;
        Bs[lk+4][lr] = b1.x; Bs[lk+5][lr] = b1.y; Bs[lk+6][lr] = b1.z; Bs[lk+7][lr] = b1.w;
        __syncthreads();
#pragma unroll
        for (int k = 0; k < BK; ++k) {
            float4 ra0 = *(const float4*)&As[k][ty*8];
            float4 ra1 = *(const float4*)&As[k][ty*8+4];
            float4 rb0 = *(const float4*)&Bs[k][tx*8];
            float4 rb1 = *(const float4*)&Bs[k][tx*8+4];
            float ra[8] = {ra0.x,ra0.y,ra0.z,ra0.w,ra1.x,ra1.y,ra1.z,ra1.w};
            float rb[8] = {rb0.x,rb0.y,rb0.z,rb0.w,rb1.x,rb1.y,rb1.z,rb1.w};
#pragma unroll
            for (int r = 0; r < 8; ++r)
#pragma unroll
                for (int c = 0; c < 8; ++c) acc[r][c] += ra[r] * rb[c];
        }
    }

    float bias[8];
#pragma unroll
    for (int c = 0; c < 8; ++c) {
        int g = g0 + tx*8 + c;
        bias[c] = bih[g] + bhh[g];
    }
#pragma unroll
    for (int r = 0; r < 8; ++r) {
        union { __hip_bfloat16 h[8]; uint4 u; } pk;
#pragma unroll
        for (int c = 0; c < 8; ++c) pk.h[c] = __float2bfloat16(acc[r][c] + bias[c]);
        *(uint4*)&xg[(size_t)(s0 + ty*8 + r) * G4 + g0 + tx*8] = pk.u;
    }
}

// ---------------- phase 2: persistent LSTM recurrence --------------------------
// 256 blocks x 256 threads, 1 block/CU. Block b owns h indices [8b, 8b+8).
// Wave w = gate w (i,f,g,o). Lane L: rg=L>>4 (2 rows), cg=L&15 (col chunks).
//
// Round-9: push the confirmed reader-serialization fix (r8: NREP 8 -> 1.44x)
// to its near-limit: NREP=64 -> 4 readers per line. Publish is still entirely
// wave 0: each of the 64 lanes issues 3 atomic exchanges (192 units = 64
// replicas x 3 self-validating {tag:16, 3x fp16} units), so the hloc handoff
// stays same-wave and no new barrier enters the serial chain. Parity
// double-buffer overwrite-safety proof unchanged (2-step separation).
__global__ __launch_bounds__(256, 1)
void lstm_rec(const float* __restrict__ Whh,
              const __hip_bfloat16* __restrict__ xg,
              float* __restrict__ hout,                 // [HDIM] final h (fp32)
              unsigned long long* __restrict__ msg)     // [2][NREP][3][NBLK], zeroed
{
    __shared__ float hsh[HDIM];
    __shared__ float gsum[4][8];
    __shared__ float xgl[32];
    __shared__ float hloc[8];

    const int t  = threadIdx.x;
    const int b  = blockIdx.x;
    const int w  = t >> 6;
    const int L  = t & 63;
    const int rg = L >> 4;
    const int cg = L & 15;
    const int rb = b & (NREP - 1);        // replica this block polls

    float4 wv[2][32];
#pragma unroll
    for (int mp = 0; mp < 2; ++mp) {
        const float* rp = Whh + (size_t)(w * HDIM + 8 * b + 2 * rg + mp) * HDIM + 4 * cg;
#pragma unroll
        for (int j = 0; j < 32; ++j) wv[mp][j] = *(const float4*)(rp + 64 * j);
    }

    float creg = 0.0f;              // cell state (meaningful for t<8 only)
    float hreg[8];
#pragma unroll
    for (int k = 0; k < 8; ++k) hreg[k] = 0.0f;   // h_0 = 0
    float xval = 0.0f;
    if (t < 32)
        xval = __bfloat162float(xg[(size_t)(t >> 3) * HDIM + 8 * b + (t & 7)]);  // s=0

    for (int s = 0; s < SEQ; ++s) {
        // stage h_s (from polled registers) + xg_s (prefetched)
        float4 hv0 = { hreg[0], hreg[1], hreg[2], hreg[3] };
        float4 hv1 = { hreg[4], hreg[5], hreg[6], hreg[7] };
        *(float4*)&hsh[8 * t]     = hv0;
        *(float4*)&hsh[8 * t + 4] = hv1;
        if (t < 32) xgl[t] = xval;
        __syncthreads();                                   // #1

        float a0 = 0.0f, a1 = 0.0f;
#pragma unroll
        for (int j = 0; j < 32; ++j) {
            float4 hv = *(const float4*)&hsh[4 * (cg + 16 * j)];
            a0 += wv[0][j].x * hv.x; a0 += wv[0][j].y * hv.y;
            a0 += wv[0][j].z * hv.z; a0 += wv[0][j].w * hv.w;
            a1 += wv[1][j].x * hv.x; a1 += wv[1][j].y * hv.y;
            a1 += wv[1][j].z * hv.z; a1 += wv[1][j].w * hv.w;
        }
#pragma unroll
        for (int mask = 1; mask <= 8; mask <<= 1) {        // reduce over cg (16 lanes)
            a0 += __shfl_xor(a0, mask, 64);
            a1 += __shfl_xor(a1, mask, 64);
        }
        if (cg == 0) { gsum[w][2 * rg] = a0; gsum[w][2 * rg + 1] = a1; }
        __syncthreads();                                   // #2

        // gates: wave 0 only; hloc handoff to the publishers (wave 0 lanes)
        // is same-wave, in-order LDS -> no barrier #3 needed.
        if (t < 8) {
            float pi = gsum[0][t] + xgl[t];
            float pf = gsum[1][t] + xgl[8 + t];
            float pg = gsum[2][t] + xgl[16 + t];
            float po = gsum[3][t] + xgl[24 + t];
            float c  = fast_sig(pf) * creg + fast_sig(pi) * fast_tanh(pg);
            creg = c;
            float h  = fast_sig(po) * fast_tanh(c);
            hloc[t] = h;
            if (s == SEQ - 1) hout[8 * b + t] = h;
        }

        if (s + 1 < SEQ) {
            const int p = (s + 1) & 1;
            // publish 3 units x NREP=64 replicas via atomic swap, all from
            // wave 0: lane L sends unit idx = k*64+L (k=0,1,2), i.e.
            // replica r = idx/3, unit j = idx%3. 3 vmem instrs total.
            if (t < 64) {
#pragma unroll
                for (int k = 0; k < 3; ++k) {
                    const int idx = k * 64 + t;
                    const int j = idx % 3, r = idx / 3;
                    float v0 = hloc[3 * j], v1 = hloc[3 * j + 1];
                    float v2 = (3 * j + 2 < 8) ? hloc[3 * j + 2] : 0.0f;
                    unsigned long long u = (unsigned long long)(unsigned short)(s + 1)
                        | ((unsigned long long)f2h(v0) << 16)
                        | ((unsigned long long)f2h(v1) << 32)
                        | ((unsigned long long)f2h(v2) << 48);
                    (void)__hip_atomic_exchange(
                            &msg[(size_t)((p * NREP + r) * 3 + j) * NBLK + b], u,
                            __ATOMIC_RELAXED, __HIP_MEMORY_SCOPE_AGENT);
                }
            }
            // prefetch xg for s+1 (latency hidden under the poll)
            if (t < 32)
                xval = __bfloat162float(xg[(size_t)(s + 1) * G4 + (size_t)(t >> 3) * HDIM + 8 * b + (t & 7)]);
            // poll block t's 3 units in THIS block's replica (4 readers/line)
            const unsigned long long* p0 = &msg[(size_t)((p * NREP + rb) * 3 + 0) * NBLK + t];
            const unsigned long long* p1 = &msg[(size_t)((p * NREP + rb) * 3 + 1) * NBLK + t];
            const unsigned long long* p2 = &msg[(size_t)((p * NREP + rb) * 3 + 2) * NBLK + t];
            const unsigned tgt = (unsigned)(s + 1);
            unsigned long long v0, v1, v2;
            do {
                v0 = __hip_atomic_load(p0, __ATOMIC_RELAXED, __HIP_MEMORY_SCOPE_AGENT);
                v1 = __hip_atomic_load(p1, __ATOMIC_RELAXED, __HIP_MEMORY_SCOPE_AGENT);
                v2 = __hip_atomic_load(p2, __ATOMIC_RELAXED, __HIP_MEMORY_SCOPE_AGENT);
            } while ((unsigned)(v0 & 0xFFFFu) < tgt ||
                     (unsigned)(v1 & 0xFFFFu) < tgt ||
                     (unsigned)(v2 & 0xFFFFu) < tgt);
            hreg[0] = h2f((unsigned short)(v0 >> 16));
            hreg[1] = h2f((unsigned short)(v0 >> 32));
            hreg[2] = h2f((unsigned short)(v0 >> 48));
            hreg[3] = h2f((unsigned short)(v1 >> 16));
            hreg[4] = h2f((unsigned short)(v1 >> 32));
            hreg[5] = h2f((unsigned short)(v1 >> 48));
            hreg[6] = h2f((unsigned short)(v2 >> 16));
            hreg[7] = h2f((unsigned short)(v2 >> 32));
        }
    }
}

// ---------------- phase 3: out[o] = h . Wfc[o,:] + bfc[o] ----------------------
__global__ __launch_bounds__(64)
void fc_kernel(const float* __restrict__ h, const float* __restrict__ Wfc,
               const float* __restrict__ bfc, float* __restrict__ out)
{
    const int o = blockIdx.x;
    const int L = threadIdx.x;
    const float* wr = Wfc + (size_t)o * HDIM;
    float s = 0.0f;
#pragma unroll
    for (int jj = 0; jj < 8; ++jj) {
        float4 wvv = *(const float4*)(wr + 4 * (L + 64 * jj));
        float4 hv  = *(const float4*)(h  + 4 * (L + 64 * jj));
        s += wvv.x * hv.x + wvv.y * hv.y + wvv.z * hv.z + wvv.w * hv.w;
    }
#pragma unroll
    for (int mask = 1; mask <= 32; mask <<= 1) s += __shfl_xor(s, mask, 64);
    if (L == 0) out[o] = s + bfc[o];
}

// ---------------- launcher -----------------------------------------------------
extern "C" void kernel_launch(void* const* d_in, const int* in_sizes, int n_in,
                              void* d_out, int out_size, void* d_ws, size_t ws_size,
                              hipStream_t stream)
{
    (void)in_sizes; (void)n_in; (void)out_size; (void)ws_size;
    const float* x   = (const float*)d_in[0];
    const float* Wih = (const float*)d_in[1];
    const float* Whh = (const float*)d_in[2];
    const float* bih = (const float*)d_in[3];
    const float* bhh = (const float*)d_in[4];
    const float* Wfc = (const float*)d_in[5];
    const float* bfc = (const float*)d_in[6];
    float* out = (float*)d_out;

    // ws layout: xg bf16 [SEQ][G4] (64 MiB) | hout fp32 [HDIM] | msg u64 [2][NREP][3][NBLK]
    __hip_bfloat16* xg       = (__hip_bfloat16*)d_ws;
    float* hout              = (float*)((char*)d_ws + (size_t)SEQ * G4 * sizeof(__hip_bfloat16));
    unsigned long long* msg  = (unsigned long long*)(hout + HDIM);

    // ws is poisoned 0xAA before every launch -> tags would read as fresh; MUST zero.
    (void)hipMemsetAsync(msg, 0, (size_t)2 * NREP * 3 * NBLK * sizeof(unsigned long long), stream);

    dim3 g1(G4 / BN, SEQ / BM);  // (64, 32)
    hipLaunchKernelGGL(xg_gemm, g1, dim3(256), 0, stream, x, Wih, bih, bhh, xg);

    // lstm_rec needs all 256 blocks co-resident. Prefer the cooperative-launch
    // guarantee; if the API refuses, fall back to a plain launch: grid==256
    // with 1 block/CU on an idle 256-CU device is co-resident by construction.
    float* hout_arg = hout;
    unsigned long long* msg_arg = msg;
    void* args[] = { (void*)&Whh, (void*)&xg, (void*)&hout_arg, (void*)&msg_arg };
    hipError_t ce = hipLaunchCooperativeKernel((const void*)lstm_rec, dim3(NBLK), dim3(256),
                                               args, 0, stream);
    if (ce != hipSuccess) {
        hipLaunchKernelGGL(lstm_rec, dim3(NBLK), dim3(256), 0, stream, Whh, xg, hout, msg);
    }

    hipLaunchKernelGGL(fc_kernel, dim3(2048), dim3(64), 0, stream, hout, Wfc, bfc, out);
}

// Round 10
// 17052.489 us; speedup vs baseline: 1.3409x; 1.3409x over previous
//
#include <hip/hip_runtime.h>
#include <hip/hip_bf16.h>
#include <hip/hip_fp16.h>

#define SEQ   4096
#define IDIM  2048
#define HDIM  2048
#define G4    8192
#define NBLK  256
#define NREP  8      // message replicas (r8 optimum): 32 readers/line, 24-unit publish

typedef __attribute__((ext_vector_type(8))) short short8;   // 8 x bf16 (4 VGPRs)
typedef __attribute__((ext_vector_type(4))) float f32x4;    // MFMA accumulator

// ---------------- numerics (v_exp2 / v_rcp based, ~1e-6 rel err) ----------------
__device__ __forceinline__ float fast_sig(float x) {
    float e = __builtin_amdgcn_exp2f(-1.4426950408889634f * x);   // exp(-x)
    return __builtin_amdgcn_rcpf(1.0f + e);
}
__device__ __forceinline__ float fast_tanh(float x) {
    float e = __builtin_amdgcn_exp2f(2.8853900817779268f * x);    // exp(2x)
    return 1.0f - 2.0f * __builtin_amdgcn_rcpf(e + 1.0f);
}
__device__ __forceinline__ unsigned short f2h(float f) {
    __half h = __float2half_rn(f);
    union { __half h; unsigned short s; } c; c.h = h; return c.s;
}
__device__ __forceinline__ float h2f(unsigned short u) {
    union { unsigned short s; __half h; } c; c.s = u; return __half2float(c.h);
}

// ---------------- phase 1: xg = x @ Wih^T + bias, bf16 MFMA ---------------------
// C[s,g] = sum_k x[s,k] * Wih[g,k]. A-frag = x rows, B-frag = Wih rows (B[k][n] =
// Wih[n][k]) -> both frags are 8 consecutive k of one row: identical
// ds_read_b128 pattern from row-major LDS tiles. Layouts per guide (m89/m91/
// m120): A/B lane L <-> [L&15][(L>>4)*8+j]; D lane L reg r <-> row=(L>>4)*4+r,
// col=L&15. fp32 global loads converted to bf16 during staging.
#define GM 128
#define GN 128
#define GK 32
#define APAD 40   // row pad: 80 B rows keep 16B alignment; 2-way LDS conflict (free)

__global__ __launch_bounds__(256, 2)
void xg_gemm(const float* __restrict__ x, const float* __restrict__ Wih,
             const float* __restrict__ bih, const float* __restrict__ bhh,
             __hip_bfloat16* __restrict__ xg)
{
    __shared__ __hip_bfloat16 As[GM][APAD];   // 10.25 KB
    __shared__ __hip_bfloat16 Bs[GN][APAD];

    const int t  = threadIdx.x;
    const int g0 = blockIdx.x * GN;           // 64 tiles over G4
    const int s0 = blockIdx.y * GM;           // 32 tiles over SEQ
    const int w  = t >> 6, L = t & 63;
    const int quad = L >> 4, lane16 = L & 15;
    const int wm = w >> 1, wn = w & 1;        // wave grid 2x2, each 64x64

    f32x4 acc[4][4];
#pragma unroll
    for (int mt = 0; mt < 4; ++mt)
#pragma unroll
        for (int nt = 0; nt < 4; ++nt) acc[mt][nt] = (f32x4){0.f, 0.f, 0.f, 0.f};

    const int srow = t >> 1, shalf = t & 1;   // staging: 128 rows x 2 halves of 16
    const float* xp = x   + (size_t)(s0 + srow) * IDIM + 16 * shalf;
    const float* wp = Wih + (size_t)(g0 + srow) * IDIM + 16 * shalf;

    for (int k0 = 0; k0 < IDIM; k0 += GK) {
        float4 a0 = *(const float4*)(xp + k0);
        float4 a1 = *(const float4*)(xp + k0 + 4);
        float4 a2 = *(const float4*)(xp + k0 + 8);
        float4 a3 = *(const float4*)(xp + k0 + 12);
        float4 b0 = *(const float4*)(wp + k0);
        float4 b1 = *(const float4*)(wp + k0 + 4);
        float4 b2 = *(const float4*)(wp + k0 + 8);
        float4 b3 = *(const float4*)(wp + k0 + 12);
        __syncthreads();
        {
            union { __hip_bfloat16 h[8]; uint4 u; } pk;
            pk.h[0]=__float2bfloat16(a0.x); pk.h[1]=__float2bfloat16(a0.y);
            pk.h[2]=__float2bfloat16(a0.z); pk.h[3]=__float2bfloat16(a0.w);
            pk.h[4]=__float2bfloat16(a1.x); pk.h[5]=__float2bfloat16(a1.y);
            pk.h[6]=__float2bfloat16(a1.z); pk.h[7]=__float2bfloat16(a1.w);
            *(uint4*)&As[srow][16 * shalf] = pk.u;
            pk.h[0]=__float2bfloat16(a2.x); pk.h[1]=__float2bfloat16(a2.y);
            pk.h[2]=__float2bfloat16(a2.z); pk.h[3]=__float2bfloat16(a2.w);
            pk.h[4]=__float2bfloat16(a3.x); pk.h[5]=__float2bfloat16(a3.y);
            pk.h[6]=__float2bfloat16(a3.z); pk.h[7]=__float2bfloat16(a3.w);
            *(uint4*)&As[srow][16 * shalf + 8] = pk.u;
            pk.h[0]=__float2bfloat16(b0.x); pk.h[1]=__float2bfloat16(b0.y);
            pk.h[2]=__float2bfloat16(b0.z); pk.h[3]=__float2bfloat16(b0.w);
            pk.h[4]=__float2bfloat16(b1.x); pk.h[5]=__float2bfloat16(b1.y);
            pk.h[6]=__float2bfloat16(b1.z); pk.h[7]=__float2bfloat16(b1.w);
            *(uint4*)&Bs[srow][16 * shalf] = pk.u;
            pk.h[0]=__float2bfloat16(b2.x); pk.h[1]=__float2bfloat16(b2.y);
            pk.h[2]=__float2bfloat16(b2.z); pk.h[3]=__float2bfloat16(b2.w);
            pk.h[4]=__float2bfloat16(b3.x); pk.h[5]=__float2bfloat16(b3.y);
            pk.h[6]=__float2bfloat16(b3.z); pk.h[7]=__float2bfloat16(b3.w);
            *(uint4*)&Bs[srow][16 * shalf + 8] = pk.u;
        }
        __syncthreads();

        short8 af[4], bf[4];
#pragma unroll
        for (int mt = 0; mt < 4; ++mt)
            af[mt] = *(const short8*)&As[wm * 64 + mt * 16 + lane16][quad * 8];
#pragma unroll
        for (int nt = 0; nt < 4; ++nt)
            bf[nt] = *(const short8*)&Bs[wn * 64 + nt * 16 + lane16][quad * 8];
#pragma unroll
        for (int mt = 0; mt < 4; ++mt)
#pragma unroll
            for (int nt = 0; nt < 4; ++nt)
                acc[mt][nt] = __builtin_amdgcn_mfma_f32_16x16x32_bf16(
                                  af[mt], bf[nt], acc[mt][nt], 0, 0, 0);
    }

#pragma unroll
    for (int nt = 0; nt < 4; ++nt) {
        const int g = g0 + wn * 64 + nt * 16 + lane16;
        const float bias = bih[g] + bhh[g];
#pragma unroll
        for (int mt = 0; mt < 4; ++mt) {
#pragma unroll
            for (int r = 0; r < 4; ++r) {
                const int so = s0 + wm * 64 + mt * 16 + quad * 4 + r;
                xg[(size_t)so * G4 + g] = __float2bfloat16(acc[mt][nt][r] + bias);
            }
        }
    }
}

// ---------------- phase 2: persistent LSTM recurrence --------------------------
// 256 blocks x 256 threads, 1 block/CU. Block b owns h indices [8b, 8b+8).
// Wave w = gate w. Lane L: rg=L>>4, cg=L&15. Sync = r8's best (NREP=8 fused
// {tag:16, 3x fp16} units, atomic-exchange publish, parity double-buffer).
//
// Round-10: CHUNKED STREAMING CONSUME. The 6144-RMW publish burst drains over
// ~1-2us, so producer visibility is staggered; r8 paid the max over all 256.
// Now wave w polls only its own 64 producers (thread t polls producer t),
// stages chunk w = h[512w..512w+512) into double-buffered hsh[s&1], and sets
// an LDS flag; the dot is split into 4 flag-gated chunks (j in [8c,8c+8) <->
// h[512c..512c+512)), so waves compute on early chunks while late producers
// are in flight. Barrier A deleted (LDS flag spins, ~30cy). Overwrite safety:
// hsh parity (reads of s-2's buffer precede barrierB(s-2) < barrierB(s-1) <
// staging(s)); msg parity (observing tag s from all producers => all blocks
// passed stage(s-1), i.e. finished reading parity-(s-1) units).
__global__ __launch_bounds__(256, 1)
void lstm_rec(const float* __restrict__ Whh,
              const __hip_bfloat16* __restrict__ xg,
              float* __restrict__ hout,                 // [HDIM] final h (fp32)
              unsigned long long* __restrict__ msg)     // [2][NREP][3][NBLK], zeroed
{
    __shared__ float hsh[2][HDIM];   // 16 KB, parity double-buffer
    __shared__ float gsum[4][8];
    __shared__ float xgl[32];
    __shared__ float hloc[8];
    __shared__ int   flag[4];        // chunk-ready step markers

    const int t  = threadIdx.x;
    const int b  = blockIdx.x;
    const int w  = t >> 6;
    const int L  = t & 63;
    const int rg = L >> 4;
    const int cg = L & 15;
    const int rb = b & (NREP - 1);   // replica this block polls

    float4 wv[2][32];
#pragma unroll
    for (int mp = 0; mp < 2; ++mp) {
        const float* rp = Whh + (size_t)(w * HDIM + 8 * b + 2 * rg + mp) * HDIM + 4 * cg;
#pragma unroll
        for (int j = 0; j < 32; ++j) wv[mp][j] = *(const float4*)(rp + 64 * j);
    }

    if (t < 4) flag[t] = -1;
    float creg = 0.0f;               // cell state (t<8 only)
    float xval = 0.0f;
    if (t < 32)
        xval = __bfloat162float(xg[(size_t)(t >> 3) * HDIM + 8 * b + (t & 7)]);  // s=0
    __syncthreads();                 // flag init visible

    for (int s = 0; s < SEQ; ++s) {
        const int pb = s & 1;

        // ---- stage chunk w of h_s into hsh[pb] (thread t <-> producer t) ----
        float f0,f1,f2,f3,f4,f5,f6,f7;
        if (s == 0) {
            f0=f1=f2=f3=f4=f5=f6=f7 = 0.0f;
        } else {
            const unsigned long long* p0 = &msg[(size_t)((pb * NREP + rb) * 3 + 0) * NBLK + t];
            const unsigned long long* p1 = &msg[(size_t)((pb * NREP + rb) * 3 + 1) * NBLK + t];
            const unsigned long long* p2 = &msg[(size_t)((pb * NREP + rb) * 3 + 2) * NBLK + t];
            const unsigned tgt = (unsigned)s;
            unsigned long long v0, v1, v2;
            do {
                v0 = __hip_atomic_load(p0, __ATOMIC_RELAXED, __HIP_MEMORY_SCOPE_AGENT);
                v1 = __hip_atomic_load(p1, __ATOMIC_RELAXED, __HIP_MEMORY_SCOPE_AGENT);
                v2 = __hip_atomic_load(p2, __ATOMIC_RELAXED, __HIP_MEMORY_SCOPE_AGENT);
            } while ((unsigned)(v0 & 0xFFFFu) < tgt ||
                     (unsigned)(v1 & 0xFFFFu) < tgt ||
                     (unsigned)(v2 & 0xFFFFu) < tgt);
            f0 = h2f((unsigned short)(v0 >> 16));
            f1 = h2f((unsigned short)(v0 >> 32));
            f2 = h2f((unsigned short)(v0 >> 48));
            f3 = h2f((unsigned short)(v1 >> 16));
            f4 = h2f((unsigned short)(v1 >> 32));
            f5 = h2f((unsigned short)(v1 >> 48));
            f6 = h2f((unsigned short)(v2 >> 16));
            f7 = h2f((unsigned short)(v2 >> 32));
        }
        float4 hv0 = { f0, f1, f2, f3 };
        float4 hv1 = { f4, f5, f6, f7 };
        *(float4*)&hsh[pb][8 * t]     = hv0;
        *(float4*)&hsh[pb][8 * t + 4] = hv1;
        if (L == 0)
            __hip_atomic_store(&flag[w], s, __ATOMIC_RELEASE, __HIP_MEMORY_SCOPE_WORKGROUP);

        // ---- dot over 4 flag-gated chunks ----
        float a0 = 0.0f, a1 = 0.0f;
#pragma unroll
        for (int c = 0; c < 4; ++c) {
            if (c != w) {
                while (__hip_atomic_load(&flag[c], __ATOMIC_ACQUIRE,
                                         __HIP_MEMORY_SCOPE_WORKGROUP) < s) {}
            }
#pragma unroll
            for (int j = 8 * c; j < 8 * c + 8; ++j) {
                float4 hv = *(const float4*)&hsh[pb][4 * (cg + 16 * j)];
                a0 += wv[0][j].x * hv.x; a0 += wv[0][j].y * hv.y;
                a0 += wv[0][j].z * hv.z; a0 += wv[0][j].w * hv.w;
                a1 += wv[1][j].x * hv.x; a1 += wv[1][j].y * hv.y;
                a1 += wv[1][j].z * hv.z; a1 += wv[1][j].w * hv.w;
            }
        }
#pragma unroll
        for (int mask = 1; mask <= 8; mask <<= 1) {        // reduce over cg
            a0 += __shfl_xor(a0, mask, 64);
            a1 += __shfl_xor(a1, mask, 64);
        }
        if (cg == 0) { gsum[w][2 * rg] = a0; gsum[w][2 * rg + 1] = a1; }
        __syncthreads();                                   // barrier B

        if (t < 32) xgl[t] = xval;                         // wave0 in-order w/ gates
        if (t < 8) {
            float pi = gsum[0][t] + xgl[t];
            float pf = gsum[1][t] + xgl[8 + t];
            float pg = gsum[2][t] + xgl[16 + t];
            float po = gsum[3][t] + xgl[24 + t];
            float c  = fast_sig(pf) * creg + fast_sig(pi) * fast_tanh(pg);
            creg = c;
            float h  = fast_sig(po) * fast_tanh(c);
            hloc[t] = h;
            if (s == SEQ - 1) hout[8 * b + t] = h;
        }

        if (s + 1 < SEQ) {
            const int p = (s + 1) & 1;
            // publish 3 units x NREP replicas via atomic swap (r8 pattern)
            if (t < 3 * NREP) {
                const int j = t % 3, r = t / 3;
                float u0 = hloc[3 * j], u1 = hloc[3 * j + 1];
                float u2 = (3 * j + 2 < 8) ? hloc[3 * j + 2] : 0.0f;
                unsigned long long u = (unsigned long long)(unsigned short)(s + 1)
                    | ((unsigned long long)f2h(u0) << 16)
                    | ((unsigned long long)f2h(u1) << 32)
                    | ((unsigned long long)f2h(u2) << 48);
                (void)__hip_atomic_exchange(
                        &msg[(size_t)((p * NREP + r) * 3 + j) * NBLK + b], u,
                        __ATOMIC_RELAXED, __HIP_MEMORY_SCOPE_AGENT);
            }
            // prefetch xg for s+1 (hidden under next iteration's poll)
            if (t < 32)
                xval = __bfloat162float(xg[(size_t)(s + 1) * G4 + (size_t)(t >> 3) * HDIM + 8 * b + (t & 7)]);
        }
    }
}

// ---------------- phase 3: out[o] = h . Wfc[o,:] + bfc[o] ----------------------
__global__ __launch_bounds__(64)
void fc_kernel(const float* __restrict__ h, const float* __restrict__ Wfc,
               const float* __restrict__ bfc, float* __restrict__ out)
{
    const int o = blockIdx.x;
    const int L = threadIdx.x;
    const float* wr = Wfc + (size_t)o * HDIM;
    float s = 0.0f;
#pragma unroll
    for (int jj = 0; jj < 8; ++jj) {
        float4 wvv = *(const float4*)(wr + 4 * (L + 64 * jj));
        float4 hv  = *(const float4*)(h  + 4 * (L + 64 * jj));
        s += wvv.x * hv.x + wvv.y * hv.y + wvv.z * hv.z + wvv.w * hv.w;
    }
#pragma unroll
    for (int mask = 1; mask <= 32; mask <<= 1) s += __shfl_xor(s, mask, 64);
    if (L == 0) out[o] = s + bfc[o];
}

// ---------------- launcher -----------------------------------------------------
extern "C" void kernel_launch(void* const* d_in, const int* in_sizes, int n_in,
                              void* d_out, int out_size, void* d_ws, size_t ws_size,
                              hipStream_t stream)
{
    (void)in_sizes; (void)n_in; (void)out_size; (void)ws_size;
    const float* x   = (const float*)d_in[0];
    const float* Wih = (const float*)d_in[1];
    const float* Whh = (const float*)d_in[2];
    const float* bih = (const float*)d_in[3];
    const float* bhh = (const float*)d_in[4];
    const float* Wfc = (const float*)d_in[5];
    const float* bfc = (const float*)d_in[6];
    float* out = (float*)d_out;

    // ws layout: xg bf16 [SEQ][G4] (64 MiB) | hout fp32 [HDIM] | msg u64 [2][NREP][3][NBLK]
    __hip_bfloat16* xg       = (__hip_bfloat16*)d_ws;
    float* hout              = (float*)((char*)d_ws + (size_t)SEQ * G4 * sizeof(__hip_bfloat16));
    unsigned long long* msg  = (unsigned long long*)(hout + HDIM);

    // ws is poisoned 0xAA before every launch -> tags would read as fresh; MUST zero.
    (void)hipMemsetAsync(msg, 0, (size_t)2 * NREP * 3 * NBLK * sizeof(unsigned long long), stream);

    dim3 g1(G4 / GN, SEQ / GM);  // (64, 32)
    hipLaunchKernelGGL(xg_gemm, g1, dim3(256), 0, stream, x, Wih, bih, bhh, xg);

    // lstm_rec needs all 256 blocks co-resident. Prefer the cooperative-launch
    // guarantee; if the API refuses, fall back to a plain launch: grid==256
    // with 1 block/CU on an idle 256-CU device is co-resident by construction.
    float* hout_arg = hout;
    unsigned long long* msg_arg = msg;
    void* args[] = { (void*)&Whh, (void*)&xg, (void*)&hout_arg, (void*)&msg_arg };
    hipError_t ce = hipLaunchCooperativeKernel((const void*)lstm_rec, dim3(NBLK), dim3(256),
                                               args, 0, stream);
    if (ce != hipSuccess) {
        hipLaunchKernelGGL(lstm_rec, dim3(NBLK), dim3(256), 0, stream, Whh, xg, hout, msg);
    }

    hipLaunchKernelGGL(fc_kernel, dim3(2048), dim3(64), 0, stream, hout, Wfc, bfc, out);
}